// Round 6
// baseline (303.114 us; speedup 1.0000x reference)
//
#include <hip/hip_runtime.h>

// Sizes (fixed by the problem)
#define S_IN 256
#define IN_PER_BATCH (S_IN * S_IN * S_IN)
#define D1_PER_BATCH (128 * 128 * 128)
#define D2_PER_BATCH (64 * 64 * 64)
#define X_ELEMS (2 * IN_PER_BATCH)
#define D1_ELEMS (2 * D1_PER_BATCH)
#define D2_ELEMS (2 * D2_PER_BATCH)

// Staged tile: 8x8x32 core, +-2 halo (z,y), x staged [x0-4, x0+35]
// Row = 40 floats = 10 float4 -> LDS byte offset of vec v is exactly 16*v
#define LXR 40
#define NROW 144                 // 12 z * 12 y real rows
#define BUFV 1536                // padded to 6 full slots of 256 lanes (>= 1440)
#define BUFF (BUFV * 4)          // 6144 floats = 24 KB
#define NBLK 16384

__device__ __forceinline__ void gload_lds16(const float* g, float* l) {
    __builtin_amdgcn_global_load_lds(
        (const __attribute__((address_space(1))) void*)g,
        (__attribute__((address_space(3))) void*)l, 16, 0, 0);
}

__global__ __launch_bounds__(256, 6) void fused_pyramid(
    const float* __restrict__ x, const float* __restrict__ k0,
    const float* __restrict__ k1, float* __restrict__ out0,
    float* __restrict__ out1, float* __restrict__ out2)
{
    __shared__ float ls[BUFF];
    __shared__ float kw1[25][8];     // 5x5x5 weights (divergent row reads)

    const int tid = threadIdx.x;

    // XCD-contiguous swizzle: 16384 = 8 * 2048 (bijective)
    const int bx  = blockIdx.x;
    const int lin = (bx & 7) * 2048 + (bx >> 3);
    const int wt = lin & 7;           // 8 x-tiles
    const int hy = (lin >> 3) & 31;   // 32 y-tiles
    const int dz = (lin >> 8) & 31;   // 32 z-tiles
    const int n  = lin >> 13;         // 2 batches

    const int x0 = wt << 5;
    const int y0 = hy << 3;
    const int z0 = dz << 3;
    const bool edge = (wt == 0);      // block-uniform

    const float* xb = x + (size_t)n * IN_PER_BATCH;

    // ---- passthrough: direct global->reg loads of the 8x8x32 core.
    // Issued BEFORE the DMA so waiting on them needs only vmcnt(<=6);
    // they hit L2/L3 (same lines the DMA fetches).
    float4 pt0, pt1;
    {
        const float* gsrc = xb + (((size_t)z0) << 16) + (y0 << 8) + x0;
        int v0 = tid,        jj0 = v0 & 7, rc0 = v0 >> 3;
        int v1 = tid + 256,  jj1 = v1 & 7, rc1 = v1 >> 3;
        pt0 = *reinterpret_cast<const float4*>(
            gsrc + (((size_t)(rc0 >> 3)) << 16) + ((rc0 & 7) << 8) + (jj0 << 2));
        pt1 = *reinterpret_cast<const float4*>(
            gsrc + (((size_t)(rc1 >> 3)) << 16) + ((rc1 & 7) << 8) + (jj1 << 2));
    }

    // ---- left-edge patch value (wt==0 only): columns gx=-2,-1 -> x[...,0]
    float pv = 0.0f;
    int plz = 0, ply = 0;
    const bool pact = edge && (tid < NROW);
    if (pact) {
        plz = tid / 12;
        ply = tid - plz * 12;
        int gz = z0 + plz - 2; gz = gz < 0 ? 0 : (gz > 255 ? 255 : gz);
        int gy = y0 + ply - 2; gy = gy < 0 ? 0 : (gy > 255 ? 255 : gy);
        pv = xb[((size_t)gz << 16) + (gy << 8)];
    }

    // d2 weights -> LDS (tiny; done before barrier)
    if (tid < 125) kw1[tid / 5][tid % 5] = k1[tid];

    // ---- issue staging DMA (wave-uniform LDS base + lane*16) ----
    {
        float* lb = ls + (tid << 2);
#pragma unroll
        for (int i = 0; i < 6; ++i) {
            int v = tid + (i << 8);
            int row = v / 10;            // 10 float4 per LDS row
            int j = v - row * 10;
            int lz = row / 12;           // pad slots clamp harmlessly
            int ly = row - lz * 12;
            int gz = z0 + lz - 2; gz = gz < 0 ? 0 : (gz > 255 ? 255 : gz);
            int gy = y0 + ly - 2; gy = gy < 0 ? 0 : (gy > 255 ? 255 : gy);
            int gx = x0 - 4 + (j << 2); gx = gx < 0 ? 0 : (gx > 252 ? 252 : gx);
            gload_lds16(xb + (((size_t)gz << 16) + (gy << 8) + gx),
                        lb + (size_t)i * 1024);
        }
    }

    // ---- store passthrough (overlaps DMA flight time) ----
    {
        float* ob0 = out0 + (size_t)n * IN_PER_BATCH
                   + (((size_t)z0) << 16) + (y0 << 8) + x0;
        int v0 = tid,        jj0 = v0 & 7, rc0 = v0 >> 3;
        int v1 = tid + 256,  jj1 = v1 & 7, rc1 = v1 >> 3;
        *reinterpret_cast<float4*>(
            &ob0[(((size_t)(rc0 >> 3)) << 16) + ((rc0 & 7) << 8) + (jj0 << 2)]) = pt0;
        *reinterpret_cast<float4*>(
            &ob0[(((size_t)(rc1 >> 3)) << 16) + ((rc1 & 7) << 8) + (jj1 << 2)]) = pt1;
    }

    __syncthreads();                   // drains vmcnt -> DMA landed
    if (edge) {
        if (pact)
            *reinterpret_cast<float2*>(
                &ls[(plz * 12 + ply) * LXR + 2]) = make_float2(pv, pv);
        __syncthreads();
    }

    if (tid < 128) {
        // ---- d1: 3x3x3 stride-2; each thread computes 2 adjacent-x outputs
        //      via aligned 2x ds_read_b128 per row (9 reads/output).
        const int p  = tid & 7;          // output pair: ox = 2p, 2p+1
        const int oy = (tid >> 3) & 3;
        const int oz = tid >> 5;         // 0..3
        const float* base = ls + ((2 * oz + 1) * 12 + (2 * oy + 1)) * LXR + (p << 2);
        float acc0 = 0.0f, acc1 = 0.0f;
#pragma unroll
        for (int a = 0; a < 3; ++a)
#pragma unroll
            for (int b = 0; b < 3; ++b) {
                const float* lr = base + (a * 12 + b) * LXR;
                float4 A  = *reinterpret_cast<const float4*>(lr);      // l[4p..4p+3]
                float4 Bv = *reinterpret_cast<const float4*>(lr + 4);  // l[4p+4..4p+7]
                float kA = k0[(a * 3 + b) * 3 + 0];   // uniform -> SGPR
                float kB = k0[(a * 3 + b) * 3 + 1];
                float kC = k0[(a * 3 + b) * 3 + 2];
                acc0 = fmaf(kA, A.w,  acc0);   // lx = 4p+3
                acc0 = fmaf(kB, Bv.x, acc0);   // lx = 4p+4
                acc0 = fmaf(kC, Bv.y, acc0);   // lx = 4p+5
                acc1 = fmaf(kA, Bv.y, acc1);   // lx = 4p+5
                acc1 = fmaf(kB, Bv.z, acc1);   // lx = 4p+6
                acc1 = fmaf(kC, Bv.w, acc1);   // lx = 4p+7
            }
        float* ob1 = out1 + (size_t)n * D1_PER_BATCH
                   + (((size_t)dz << 2) << 14) + ((hy << 2) << 7) + (wt << 4);
        *reinterpret_cast<float2*>(
            &ob1[(oz << 14) + (oy << 7) + (p << 1)]) = make_float2(acc0, acc1);
    } else {
        // ---- d2: 5x5x5 stride-4 -> 2x2x8 outputs, 4 threads/output ----
        const int t = tid - 128;
        const int q = t & 3;             // splits the 25 (a,b) rows
        const int o = t >> 2;            // 0..31
        const int ox = o & 7, oy = (o >> 3) & 1, oz = o >> 4;
        float acc = 0.0f;
#pragma unroll
        for (int m = 0; m < 7; ++m) {
            int r = q + (m << 2);
            if (r < 25) {
                int a = r / 5, b = r - 5 * a;
                const float* lr = ls + ((4 * oz + a) * 12 + (4 * oy + b)) * LXR + (ox << 2);
                float4 A4 = *reinterpret_cast<const float4*>(lr);
                float4 B4 = *reinterpret_cast<const float4*>(lr + 4);
                float4 kr = *reinterpret_cast<const float4*>(&kw1[r][0]);
                float k4 = kw1[r][4];
                acc = fmaf(kr.x, A4.z, acc);   // lx = 4ox+2
                acc = fmaf(kr.y, A4.w, acc);
                acc = fmaf(kr.z, B4.x, acc);
                acc = fmaf(kr.w, B4.y, acc);
                acc = fmaf(k4,   B4.z, acc);   // lx = 4ox+6
            }
        }
        acc += __shfl_xor(acc, 1);
        acc += __shfl_xor(acc, 2);
        if (q == 0) {
            float* ob2 = out2 + (size_t)n * D2_PER_BATCH
                       + (((size_t)dz << 1) << 12) + ((hy << 1) << 6) + (wt << 3);
            ob2[(oz << 12) + (oy << 6) + ox] = acc;
        }
    }
}

extern "C" void kernel_launch(void* const* d_in, const int* in_sizes, int n_in,
                              void* d_out, int out_size, void* d_ws, size_t ws_size,
                              hipStream_t stream) {
    const float* x  = (const float*)d_in[0];
    const float* k0 = (const float*)d_in[1];   // 27 floats (3x3x3)
    const float* k1 = (const float*)d_in[2];   // 125 floats (5x5x5)

    float* out0 = (float*)d_out;               // x passthrough
    float* out1 = out0 + X_ELEMS;              // d1
    float* out2 = out1 + D1_ELEMS;             // d2

    fused_pyramid<<<NBLK, 256, 0, stream>>>(x, k0, k1, out0, out1, out2);
}